// Round 2
// baseline (122.546 us; speedup 1.0000x reference)
//
#include <hip/hip_runtime.h>
#include <math.h>

// Problem constants (from reference)
#define BB 4
#define HH 512
#define WW 512
#define CC 32      // channels; 32 floats = 8 float4 = 128 B per point
#define HO 256
#define WO 256
// Output positions: BB*HO*WO = 262144; out_size = *CC = 8388608 floats

// Fill index grid with zeros (0 == empty). int4-vectorized.
__global__ void fill_zero_kernel(int4* __restrict__ g, int n4) {
    int i = blockIdx.x * blockDim.x + threadIdx.x;
    if (i < n4) g[i] = make_int4(0, 0, 0, 0);
}

// Scatter point index+1 into dense (B,H,W) int grid.
__global__ void scatter_idx_kernel(const int* __restrict__ coors,
                                   int* __restrict__ grid, int n) {
    int i = blockIdx.x * blockDim.x + threadIdx.x;
    if (i >= n) return;
    int b = coors[i * 3 + 0];
    int y = coors[i * 3 + 1];
    int x = coors[i * 3 + 2];
    grid[((size_t)b * HH + y) * WW + x] = i + 1;
}

// 8 lanes per output position (lane = channel group of 4 floats).
// Each lane gathers <=9 float4s (its channel slice of each window point),
// max-reduces in one float4, -inf -> 0 on store.
// Feature loads: 8 lanes of a group read one contiguous 128 B row.
__global__ void __launch_bounds__(256)
pool_kernel(const float4* __restrict__ feat,   // N x 8 float4
            const int* __restrict__ grid,      // B*H*W
            float4* __restrict__ out) {        // B*HO*WO x 8 float4
    int tid = blockIdx.x * blockDim.x + threadIdx.x;
    int cg  = tid & 7;          // channel group 0..7
    int pos = tid >> 3;         // output position
    // grid sized exactly: pos < BB*HO*WO

    int ox = pos & (WO - 1);
    int t  = pos >> 8;          // / WO
    int oy = t & (HO - 1);
    int b  = t >> 8;            // / HO

    const float NEG = -INFINITY;
    float4 acc = make_float4(NEG, NEG, NEG, NEG);

    int iy0 = 2 * oy - 1;
    int ix0 = 2 * ox - 1;
    const int* gb = grid + (size_t)b * (HH * WW);

#pragma unroll
    for (int dy = 0; dy < 3; ++dy) {
        int iy = iy0 + dy;
        if ((unsigned)iy >= (unsigned)HH) continue;
        const int* grow = gb + iy * WW;
#pragma unroll
        for (int dx = 0; dx < 3; ++dx) {
            int ix = ix0 + dx;
            if ((unsigned)ix >= (unsigned)WW) continue;
            int idx = grow[ix];
            if (idx != 0) {
                float4 v = feat[(size_t)(idx - 1) * 8 + cg];
                acc.x = fmaxf(acc.x, v.x);
                acc.y = fmaxf(acc.y, v.y);
                acc.z = fmaxf(acc.z, v.z);
                acc.w = fmaxf(acc.w, v.w);
            }
        }
    }

    acc.x = isinf(acc.x) ? 0.0f : acc.x;
    acc.y = isinf(acc.y) ? 0.0f : acc.y;
    acc.z = isinf(acc.z) ? 0.0f : acc.z;
    acc.w = isinf(acc.w) ? 0.0f : acc.w;
    out[(size_t)pos * 8 + cg] = acc;
}

extern "C" void kernel_launch(void* const* d_in, const int* in_sizes, int n_in,
                              void* d_out, int out_size, void* d_ws, size_t ws_size,
                              hipStream_t stream) {
    const float* features = (const float*)d_in[0];   // N x 32 fp32
    const int*   coors    = (const int*)d_in[1];     // N x 3 int32
    int n = in_sizes[0] / CC;                        // N = 300000

    int* grid = (int*)d_ws;                          // B*H*W int32 = 4 MiB

    // 1) zero the index grid (0xAA-poisoned every timed call)
    {
        int n4 = (BB * HH * WW) / 4;                 // 262144 int4
        int blk = 256, grd = (n4 + blk - 1) / blk;
        fill_zero_kernel<<<grd, blk, 0, stream>>>((int4*)grid, n4);
    }
    // 2) scatter indices
    {
        int blk = 256, grd = (n + blk - 1) / blk;
        scatter_idx_kernel<<<grd, blk, 0, stream>>>(coors, grid, n);
    }
    // 3) pool: 8 threads per output position
    {
        int nthreads = BB * HO * WO * 8;             // 2,097,152
        int blk = 256, grd = nthreads / blk;         // 8192 blocks
        pool_kernel<<<grd, blk, 0, stream>>>((const float4*)features, grid,
                                             (float4*)d_out);
    }
}

// Round 3
// 114.217 us; speedup vs baseline: 1.0729x; 1.0729x over previous
//
#include <hip/hip_runtime.h>
#include <math.h>

// Problem constants (from reference)
#define BB 4
#define HH 512
#define WW 512
#define CC 32      // channels; 32 floats = 8 float4 = 128 B per point
#define HO 256
#define WO 256

// Fill index grid with zeros (0 == empty). int4-vectorized.
__global__ void fill_zero_kernel(int4* __restrict__ g, int n4) {
    int i = blockIdx.x * blockDim.x + threadIdx.x;
    if (i < n4) g[i] = make_int4(0, 0, 0, 0);
}

// Scatter point index+1 into dense (B,H,W) int grid.
__global__ void scatter_idx_kernel(const int* __restrict__ coors,
                                   int* __restrict__ grid, int n) {
    int i = blockIdx.x * blockDim.x + threadIdx.x;
    if (i >= n) return;
    int b = coors[i * 3 + 0];
    int y = coors[i * 3 + 1];
    int x = coors[i * 3 + 2];
    grid[((size_t)b * HH + y) * WW + x] = i + 1;
}

// Block = 32 consecutive output-x positions (one oy, one b) x 8 channel
// groups. Grid window (3 rows x 65 cols) staged once through LDS; each
// lane then issues <=9 independent float4 feature gathers (8 lanes of a
// group cover one contiguous 128 B feature row) and one coalesced store.
__global__ void __launch_bounds__(256)
pool_kernel(const float4* __restrict__ feat,   // N x 8 float4
            const int* __restrict__ grid,      // B*H*W
            float4* __restrict__ out) {        // B*HO*WO x 8 float4
    // blockIdx.x: [b(2b) | oy(8b) | ox_tile(3b)]
    int ox_base = (blockIdx.x & 7) * 32;
    int oy      = (blockIdx.x >> 3) & (HO - 1);
    int b       = blockIdx.x >> 11;

    int tid = threadIdx.x;
    int cg  = tid & 7;          // channel group 0..7
    int p   = tid >> 3;         // local position 0..31

    int iy0 = 2 * oy - 1;
    int gx0 = 2 * ox_base - 1;
    const int* gb = grid + (size_t)b * (HH * WW);

    __shared__ int sg[3 * 66];  // 3 rows, pitch 66 (pad)

    if (tid < 195) {
        int r = tid / 65;       // 0..2
        int c = tid - r * 65;   // 0..64
        int iy = iy0 + r;
        int gx = gx0 + c;
        int v = 0;
        if ((unsigned)iy < (unsigned)HH && (unsigned)gx < (unsigned)WW)
            v = gb[iy * WW + gx];
        sg[r * 66 + c] = v;
    }
    __syncthreads();

    const float NEG = -INFINITY;
    float4 acc = make_float4(NEG, NEG, NEG, NEG);
    int lc = 2 * p;             // local col base; window cols lc..lc+2

#pragma unroll
    for (int dy = 0; dy < 3; ++dy) {
#pragma unroll
        for (int dx = 0; dx < 3; ++dx) {
            int v = sg[dy * 66 + lc + dx];
            if (v != 0) {
                float4 f = feat[(size_t)(v - 1) * 8 + cg];
                acc.x = fmaxf(acc.x, f.x);
                acc.y = fmaxf(acc.y, f.y);
                acc.z = fmaxf(acc.z, f.z);
                acc.w = fmaxf(acc.w, f.w);
            }
        }
    }

    acc.x = isinf(acc.x) ? 0.0f : acc.x;
    acc.y = isinf(acc.y) ? 0.0f : acc.y;
    acc.z = isinf(acc.z) ? 0.0f : acc.z;
    acc.w = isinf(acc.w) ? 0.0f : acc.w;

    int pos = ((b * HO + oy) * WO + ox_base + p);
    out[(size_t)pos * 8 + cg] = acc;
}

extern "C" void kernel_launch(void* const* d_in, const int* in_sizes, int n_in,
                              void* d_out, int out_size, void* d_ws, size_t ws_size,
                              hipStream_t stream) {
    const float* features = (const float*)d_in[0];   // N x 32 fp32
    const int*   coors    = (const int*)d_in[1];     // N x 3 int32
    int n = in_sizes[0] / CC;                        // N = 300000

    int* grid = (int*)d_ws;                          // B*H*W int32 = 4 MiB

    // 1) zero the index grid (0xAA-poisoned every timed call)
    {
        int n4 = (BB * HH * WW) / 4;                 // 262144 int4
        int blk = 256, grd = (n4 + blk - 1) / blk;
        fill_zero_kernel<<<grd, blk, 0, stream>>>((int4*)grid, n4);
    }
    // 2) scatter indices
    {
        int blk = 256, grd = (n + blk - 1) / blk;
        scatter_idx_kernel<<<grd, blk, 0, stream>>>(coors, grid, n);
    }
    // 3) pool: 8192 blocks of 256 threads (32 positions x 8 channel groups)
    {
        int grd = BB * HO * (WO / 32);               // 8192
        pool_kernel<<<grd, 256, 0, stream>>>((const float4*)features, grid,
                                             (float4*)d_out);
    }
}

// Round 4
// 109.497 us; speedup vs baseline: 1.1192x; 1.0431x over previous
//
#include <hip/hip_runtime.h>
#include <math.h>

// Problem constants (from reference)
#define BB 4
#define HH 512
#define WW 512
#define CC 32      // channels; 32 floats = 8 float4 = 128 B per point
#define HO 256
#define WO 256

// Fill index grid with zeros (0 == empty). int4-vectorized.
__global__ void fill_zero_kernel(int4* __restrict__ g, int n4) {
    int i = blockIdx.x * blockDim.x + threadIdx.x;
    if (i < n4) g[i] = make_int4(0, 0, 0, 0);
}

// Scatter point index+1 into dense (B,H,W) int grid.
__global__ void scatter_idx_kernel(const int* __restrict__ coors,
                                   int* __restrict__ grid, int n) {
    int i = blockIdx.x * blockDim.x + threadIdx.x;
    if (i >= n) return;
    int b = coors[i * 3 + 0];
    int y = coors[i * 3 + 1];
    int x = coors[i * 3 + 2];
    grid[((size_t)b * HH + y) * WW + x] = i + 1;
}

// Block = 32 consecutive output-x positions (one oy, one b) x 8 channel
// groups. Grid window (3 rows x 65 cols) staged once through LDS.
// BRANCHLESS gather: all 9 feature loads issued unconditionally (empty
// cells clamp to row 0 -> L1 broadcast), results masked to -inf via
// cndmask before the fmax tree. 9 loads in flight per lane.
__global__ void __launch_bounds__(256)
pool_kernel(const float4* __restrict__ feat,   // N x 8 float4
            const int* __restrict__ grid,      // B*H*W
            float4* __restrict__ out) {        // B*HO*WO x 8 float4
    // blockIdx.x: [b(2b) | oy(8b) | ox_tile(3b)]
    int ox_base = (blockIdx.x & 7) * 32;
    int oy      = (blockIdx.x >> 3) & (HO - 1);
    int b       = blockIdx.x >> 11;

    int tid = threadIdx.x;
    int cg  = tid & 7;          // channel group 0..7
    int p   = tid >> 3;         // local position 0..31

    int iy0 = 2 * oy - 1;
    int gx0 = 2 * ox_base - 1;
    const int* gb = grid + (size_t)b * (HH * WW);

    __shared__ int sg[3 * 66];  // 3 rows, pitch 66 (pad)

    if (tid < 195) {
        int r = tid / 65;       // 0..2
        int c = tid - r * 65;   // 0..64
        int iy = iy0 + r;
        int gx = gx0 + c;
        int v = 0;
        if ((unsigned)iy < (unsigned)HH && (unsigned)gx < (unsigned)WW)
            v = gb[iy * WW + gx];
        sg[r * 66 + c] = v;
    }
    __syncthreads();

    int lc = 2 * p;             // local col base; window cols lc..lc+2

    // 1) read 9 window indices from LDS
    int v[9];
#pragma unroll
    for (int dy = 0; dy < 3; ++dy)
#pragma unroll
        for (int dx = 0; dx < 3; ++dx)
            v[dy * 3 + dx] = sg[dy * 66 + lc + dx];

    // 2) issue all 9 loads unconditionally (empty -> row 0, broadcast)
    float4 f[9];
#pragma unroll
    for (int k = 0; k < 9; ++k) {
        int r = v[k] - 1;
        r = r < 0 ? 0 : r;
        f[k] = feat[(size_t)r * 8 + cg];
    }

    // 3) mask empties to -inf, fmax-reduce
    const float NEG = -INFINITY;
    float4 acc = make_float4(NEG, NEG, NEG, NEG);
#pragma unroll
    for (int k = 0; k < 9; ++k) {
        bool ok = v[k] != 0;
        acc.x = fmaxf(acc.x, ok ? f[k].x : NEG);
        acc.y = fmaxf(acc.y, ok ? f[k].y : NEG);
        acc.z = fmaxf(acc.z, ok ? f[k].z : NEG);
        acc.w = fmaxf(acc.w, ok ? f[k].w : NEG);
    }

    acc.x = isinf(acc.x) ? 0.0f : acc.x;
    acc.y = isinf(acc.y) ? 0.0f : acc.y;
    acc.z = isinf(acc.z) ? 0.0f : acc.z;
    acc.w = isinf(acc.w) ? 0.0f : acc.w;

    int pos = ((b * HO + oy) * WO + ox_base + p);
    out[(size_t)pos * 8 + cg] = acc;
}

extern "C" void kernel_launch(void* const* d_in, const int* in_sizes, int n_in,
                              void* d_out, int out_size, void* d_ws, size_t ws_size,
                              hipStream_t stream) {
    const float* features = (const float*)d_in[0];   // N x 32 fp32
    const int*   coors    = (const int*)d_in[1];     // N x 3 int32
    int n = in_sizes[0] / CC;                        // N = 300000

    int* grid = (int*)d_ws;                          // B*H*W int32 = 4 MiB

    // 1) zero the index grid (0xAA-poisoned every timed call)
    {
        int n4 = (BB * HH * WW) / 4;                 // 262144 int4
        int blk = 256, grd = (n4 + blk - 1) / blk;
        fill_zero_kernel<<<grd, blk, 0, stream>>>((int4*)grid, n4);
    }
    // 2) scatter indices
    {
        int blk = 256, grd = (n + blk - 1) / blk;
        scatter_idx_kernel<<<grd, blk, 0, stream>>>(coors, grid, n);
    }
    // 3) pool: 8192 blocks of 256 threads (32 positions x 8 channel groups)
    {
        int grd = BB * HO * (WO / 32);               // 8192
        pool_kernel<<<grd, 256, 0, stream>>>((const float4*)features, grid,
                                             (float4*)d_out);
    }
}